// Round 12
// baseline (754.342 us; speedup 1.0000x reference)
//
#include <hip/hip_runtime.h>
#include <math.h>

// Problem constants (fixed by the reference)
#define Bdim 1024
#define DEPTHC 6

typedef __attribute__((ext_vector_type(8))) _Float16 f16x8;
typedef __attribute__((ext_vector_type(4))) float f32x4;

__device__ __forceinline__ unsigned short f2h(float x) {
    _Float16 h = (_Float16)x;
    unsigned short u;
    __builtin_memcpy(&u, &h, 2);
    return u;
}
__device__ __forceinline__ float h2f(unsigned short u) {
    _Float16 h;
    __builtin_memcpy(&h, &u, 2);
    return (float)h;
}
__device__ __forceinline__ float sigmf(float x) { return 1.0f / (1.0f + expf(-x)); }

__device__ __forceinline__ void glds16(const void* g, void* l) {
    __builtin_amdgcn_global_load_lds(
        (const __attribute__((address_space(1))) unsigned int*)g,
        (__attribute__((address_space(3))) unsigned int*)l, 16, 0, 0);
}

// raw barrier (no implicit vmcnt drain) + counted vmcnt waits
__device__ __forceinline__ void sbar() { asm volatile("s_barrier" ::: "memory"); }
template<int N> __device__ __forceinline__ void vmwait() {
    static_assert(N == 0 || N == 4 || N == 6 || N == 8 || N == 10, "unsupported vmcnt");
    if constexpr (N == 0)  asm volatile("s_waitcnt vmcnt(0)" ::: "memory");
    if constexpr (N == 4)  asm volatile("s_waitcnt vmcnt(4)" ::: "memory");
    if constexpr (N == 6)  asm volatile("s_waitcnt vmcnt(6)" ::: "memory");
    if constexpr (N == 8)  asm volatile("s_waitcnt vmcnt(8)" ::: "memory");
    if constexpr (N == 10) asm volatile("s_waitcnt vmcnt(10)" ::: "memory");
    __builtin_amdgcn_sched_barrier(0);
}

// Preorder index of node (level, q) in a full binary tree of depth DEPTHC.
__device__ __forceinline__ int preorder_idx(int level, int q) {
    int idx = 0, rem = DEPTHC;
    for (int k = level - 1; k >= 0; --k) {
        int b = (q >> k) & 1;
        idx += 1 + b * ((1 << (rem - 1)) - 1);
        rem--;
    }
    return idx;
}

// ---------------------------------------------------------------------------
// fp32 -> fp16 converter. mode=0: dst[r*k+c]. mode=1: dst[r*2k+c]=v, zero pad.
// mode=2: fp32->fp32 TRANSPOSE of ga_wx [3][256][32] -> gaT [3][32][256].
// ---------------------------------------------------------------------------
struct CvtEnt { const float* src; unsigned short* dst; int n; int klog2; int mode; };
struct CvtArgs { CvtEnt e[10]; };

__global__ __launch_bounds__(256) void cvt_f16(CvtArgs a) {
    CvtEnt E = a.e[blockIdx.y];
    const int k = 1 << E.klog2;
    for (int t = blockIdx.x * 256 + threadIdx.x; t < E.n; t += gridDim.x * 256) {
        const float x = E.src[t];
        if (E.mode == 0) {
            const int r = t >> E.klog2, c = t & (k - 1);
            E.dst[(size_t)r * k + c] = f2h(x);
        } else if (E.mode == 1) {
            const int r = t >> E.klog2, c = t & (k - 1);
            E.dst[(size_t)r * 2 * k + c] = f2h(x);
            E.dst[(size_t)r * 2 * k + k + c] = 0;
        } else {
            // transpose [3][256][32] -> [3][32][256], fp32
            float* df = (float*)E.dst;
            const int g = t >> 13, rem = t & 8191;
            const int j = rem >> 5, kk = rem & 31;
            df[(g << 13) + (kk << 8) + j] = x;
        }
    }
}

// ---------------------------------------------------------------------------
// fp16 MFMA GEMM body: C = A @ W^T + bias, K=256, 4 K-steps of BK=64.
// Tile BM x 128, 4 waves. Counted-vmcnt double-buffered pipeline.
// ---------------------------------------------------------------------------
template<int BM>
__device__ __forceinline__ void gemm_body(
    int m0, int col0,
    const unsigned short* __restrict__ A2, const unsigned short* __restrict__ W2,
    const float* __restrict__ bias, float* __restrict__ Cf, int Nf,
    unsigned short* __restrict__ C2, int outStride, int outOffset,
    unsigned short* As, unsigned short* Ws)
{
    constexpr int MF = BM / 32;
    constexpr int AI = BM / 32;
    constexpr int ASZ = BM * 64;

    const int tid = threadIdx.x;
    const int w = tid >> 6, lane = tid & 63;
    const int p = m0 >> 10;
    const int wm = (w >> 1) * (BM / 2), wn = (w & 1) << 6;

    f32x4 acc[MF][4] = {};

    auto stage = [&](int buf, int s) {
        const int ka = s << 6;
        #pragma unroll
        for (int i = 0; i < AI; ++i) {
            const int r = w * (BM / 4) + (i << 3) + (lane >> 3);
            const int sl = (lane & 7) ^ (r & 7);
            glds16(A2 + (size_t)(m0 + r) * 256 + ka + (sl << 3),
                   &As[buf * ASZ + ((w * (BM / 4) + (i << 3)) << 6)]);
        }
        #pragma unroll
        for (int i = 0; i < 4; ++i) {
            const int r = (w << 5) + (i << 3) + (lane >> 3);
            const int sl = (lane & 7) ^ (r & 7);
            glds16(W2 + (size_t)(col0 + r) * 256 + ka + (sl << 3),
                   &Ws[buf * 8192 + (w << 11) + (i << 9)]);
        }
    };
    auto compute = [&](int buf) {
        #pragma unroll
        for (int kk = 0; kk < 2; ++kk) {
            f16x8 af[MF], bw[4];
            #pragma unroll
            for (int mf = 0; mf < MF; ++mf) {
                const int row = wm + (mf << 4) + (lane & 15);
                const int sl = (((kk << 2) | (lane >> 4)) ^ (row & 7)) << 3;
                af[mf] = *(const f16x8*)&As[buf * ASZ + (row << 6) + sl];
            }
            #pragma unroll
            for (int nf = 0; nf < 4; ++nf) {
                const int row = wn + (nf << 4) + (lane & 15);
                const int sl = (((kk << 2) | (lane >> 4)) ^ (row & 7)) << 3;
                bw[nf] = *(const f16x8*)&Ws[buf * 8192 + (row << 6) + sl];
            }
            __builtin_amdgcn_s_setprio(1);
            #pragma unroll
            for (int mf = 0; mf < MF; ++mf)
                #pragma unroll
                for (int nf = 0; nf < 4; ++nf)
                    acc[mf][nf] = __builtin_amdgcn_mfma_f32_16x16x32_f16(
                        af[mf], bw[nf], acc[mf][nf], 0, 0, 0);
            __builtin_amdgcn_s_setprio(0);
        }
    };

    stage(0, 0);
    #pragma unroll
    for (int s = 0; s < 4; ++s) {
        if (s + 1 < 4) { stage((s + 1) & 1, s + 1); vmwait<AI + 4>(); }
        else           { vmwait<0>(); }
        sbar();
        compute(s & 1);
        sbar();
    }

    const size_t oBase = (((size_t)(p * outStride + outOffset)) << 10) + (m0 & 1023);
    #pragma unroll
    for (int nf = 0; nf < 4; ++nf) {
        const int col = col0 + wn + (nf << 4) + (lane & 15);
        const float bj = bias[col];
        #pragma unroll
        for (int mf = 0; mf < MF; ++mf) {
            const int rb = wm + (mf << 4) + ((lane >> 4) << 2);
            #pragma unroll
            for (int r = 0; r < 4; ++r) {
                const float v = acc[mf][nf][r] + bj;
                const size_t orow = oBase + rb + r;
                if (Cf) Cf[orow * (size_t)Nf + col] = v;
                if (C2) C2[orow * 256 + col] = f2h(v);
            }
        }
    }
}

template<int BM>
__global__ __launch_bounds__(256) void mfma_gemm(
    const unsigned short* __restrict__ A2, const unsigned short* __restrict__ W2,
    const float* __restrict__ bias, float* __restrict__ Cf, int Nf,
    unsigned short* __restrict__ C2, int outStride, int outOffset)
{
    __shared__ __attribute__((aligned(16))) unsigned short As[2 * BM * 64];
    __shared__ __attribute__((aligned(16))) unsigned short Ws[2 * 8192];
    gemm_body<BM>(blockIdx.x * BM, blockIdx.y * 128, A2, W2, bias, Cf, Nf, C2,
                  outStride, outOffset, As, Ws);
}

// Multi-GEMM: up to 3 independent GEMMs in one dispatch (flattened 1D grid).
struct GDesc {
    const unsigned short* A; const unsigned short* W; const float* bias;
    float* Cf; int Nf; unsigned short* C2; int outStride; int outOffset; int nbm;
};
struct GMulti { GDesc d[3]; int n0; int n01; };

template<int BM>
__global__ __launch_bounds__(256) void mfma_gemm_multi(GMulti g) {
    __shared__ __attribute__((aligned(16))) unsigned short As[2 * BM * 64];
    __shared__ __attribute__((aligned(16))) unsigned short Ws[2 * 8192];
    const int id = blockIdx.x;
    int di, base;
    if (id < g.n0)       { di = 0; base = 0; }
    else if (id < g.n01) { di = 1; base = g.n0; }
    else                 { di = 2; base = g.n01; }
    const GDesc D = g.d[di];
    const int lid = id - base;
    gemm_body<BM>((lid % D.nbm) * BM, (lid / D.nbm) * 128, D.A, D.W, D.bias,
                  D.Cf, D.Nf, D.C2, D.outStride, D.outOffset, As, Ws);
}

// ---------------------------------------------------------------------------
// MFMA pred + softmax (+ optional gru_a), block-partitioned.
// pred blocks [0,npred): BM=128 rows, 4 waves x 32 rows x 32 cols.
// gru_a blocks [npred,...): x-dots K=32 with TRANSPOSED gaT [3][32][256]
//   (coalesced), sps staged in LDS [16][36] read as float4; h-parts from GhA;
//   frag-packed fp16 output ApfP.
// ---------------------------------------------------------------------------
__global__ __launch_bounds__(256) void pred_mfma_grua(
    const unsigned short* __restrict__ H2, const unsigned short* __restrict__ h2o2,
    const float* __restrict__ h2o_b, float* __restrict__ out,
    unsigned short* __restrict__ SP2, int level, int nodeStride, int nodeOffset,
    int npred,
    const unsigned short* __restrict__ SP2c, const float* __restrict__ GhA,
    const float* __restrict__ gaT, const float* __restrict__ bx,
    const float* __restrict__ ha, unsigned short* __restrict__ ApfP)
{
    __shared__ __attribute__((aligned(16))) unsigned short As[2 * 8192];   // 2 x 128x64
    __shared__ __attribute__((aligned(16))) unsigned short Wsm[8192];      // 4 steps x 32x64

    const int tid = threadIdx.x;
    const int w = tid >> 6, lane = tid & 63;

    if ((int)blockIdx.x < npred) {
        const int m0g = blockIdx.x * 128;
        const int p = m0g >> 10;
        const int q = p * nodeStride + nodeOffset;
        const int b0 = m0g & 1023;
        const size_t aBase = ((size_t)q << 10) + b0;

        // one-time weight stage: wave w stages its K-step w (32 rows x 64)
        #pragma unroll
        for (int i = 0; i < 4; ++i) {
            const int r = (i << 3) + (lane >> 3);
            const int sl = (lane & 7) ^ (r & 7);
            glds16(h2o2 + (size_t)r * 256 + (w << 6) + (sl << 3),
                   &Wsm[(w << 11) + (i << 9)]);
        }

        auto stageA = [&](int buf, int s) {
            #pragma unroll
            for (int i = 0; i < 4; ++i) {
                const int r = (w << 5) + (i << 3) + (lane >> 3);
                const int sl = (lane & 7) ^ (r & 7);
                glds16(H2 + (aBase + r) * 256 + (s << 6) + (sl << 3),
                       &As[buf * 8192 + (((w << 5) + (i << 3)) << 6)]);
            }
        };

        f32x4 acc[2][2] = {};

        auto compute = [&](int buf, int s) {
            #pragma unroll
            for (int kk = 0; kk < 2; ++kk) {
                f16x8 af[2], bw[2];
                #pragma unroll
                for (int mf = 0; mf < 2; ++mf) {
                    const int row = (w << 5) + (mf << 4) + (lane & 15);
                    const int sl = (((kk << 2) | (lane >> 4)) ^ (row & 7)) << 3;
                    af[mf] = *(const f16x8*)&As[buf * 8192 + (row << 6) + sl];
                }
                #pragma unroll
                for (int nf = 0; nf < 2; ++nf) {
                    const int rowb = (nf << 4) + (lane & 15);
                    const int sl = (((kk << 2) | (lane >> 4)) ^ (rowb & 7)) << 3;
                    bw[nf] = *(const f16x8*)&Wsm[(s << 11) + (rowb << 6) + sl];
                }
                __builtin_amdgcn_s_setprio(1);
                #pragma unroll
                for (int mf = 0; mf < 2; ++mf)
                    #pragma unroll
                    for (int nf = 0; nf < 2; ++nf)
                        acc[mf][nf] = __builtin_amdgcn_mfma_f32_16x16x32_f16(
                            af[mf], bw[nf], acc[mf][nf], 0, 0, 0);
                __builtin_amdgcn_s_setprio(0);
            }
        };

        stageA(0, 0);
        #pragma unroll
        for (int s = 0; s < 4; ++s) {
            if (s + 1 < 4) { stageA((s + 1) & 1, s + 1); vmwait<4>(); }
            else           { vmwait<0>(); }
            sbar();
            compute(s & 1, s);
            sbar();
        }

        const int idx = preorder_idx(level, q);
        const int colb = lane & 15;
        const float bj0 = h2o_b[colb];
        const float bj1 = h2o_b[16 + colb];

        #pragma unroll
        for (int mf = 0; mf < 2; ++mf) {
            #pragma unroll
            for (int r = 0; r < 4; ++r) {
                const int rowl = (w << 5) + (mf << 4) + ((lane >> 4) << 2) + r;
                const int b = b0 + rowl;
                const float v0 = acc[mf][0][r] + bj0;
                const float v1 = acc[mf][1][r] + bj1;
                const size_t obase = (((size_t)idx << 10) + b) * 32;
                out[obase + colb] = v0;
                out[obase + 16 + colb] = v1;
                float mx = fmaxf(v0, v1);
                #pragma unroll
                for (int off = 8; off > 0; off >>= 1) mx = fmaxf(mx, __shfl_xor(mx, off, 16));
                const float e0 = expf(v0 - mx), e1 = expf(v1 - mx);
                float sum = e0 + e1;
                #pragma unroll
                for (int off = 8; off > 0; off >>= 1) sum += __shfl_xor(sum, off, 16);
                const float inv = 1.0f / sum;
                const size_t sbase = (((size_t)q << 10) + b) * 64;
                SP2[sbase + colb] = f2h(e0 * inv);
                SP2[sbase + 16 + colb] = f2h(e1 * inv);
                SP2[sbase + 32 + colb] = 0;
                SP2[sbase + 48 + colb] = 0;
            }
        }
    } else {
        // gru_a part: transposed coalesced gaT reads + float4 sps broadcasts
        float (*sps)[36] = (float(*)[36])As;    // 16*36*4 = 2304 B
        const int bid = blockIdx.x - npred;
        const int m0  = bid * 16;

        for (int t = tid; t < 16 * 32; t += 256) {
            const int r = t >> 5, k = t & 31;
            sps[r][k] = h2f(SP2c[((size_t)(m0 + r)) * 64 + k]);
        }
        __syncthreads();

        const int j = tid;
        float accr[16] = {}, accz[16] = {}, accn[16] = {};
        #pragma unroll
        for (int k4 = 0; k4 < 32; k4 += 4) {
            float wr_[4], wz_[4], wn_[4];
            #pragma unroll
            for (int u = 0; u < 4; ++u) {
                wr_[u] = gaT[(k4 + u) * 256 + j];
                wz_[u] = gaT[8192 + (k4 + u) * 256 + j];
                wn_[u] = gaT[16384 + (k4 + u) * 256 + j];
            }
            #pragma unroll
            for (int r = 0; r < 16; ++r) {
                const float4 s4 = *(const float4*)&sps[r][k4];
                accr[r] = fmaf(s4.x, wr_[0], accr[r]);
                accr[r] = fmaf(s4.y, wr_[1], accr[r]);
                accr[r] = fmaf(s4.z, wr_[2], accr[r]);
                accr[r] = fmaf(s4.w, wr_[3], accr[r]);
                accz[r] = fmaf(s4.x, wz_[0], accz[r]);
                accz[r] = fmaf(s4.y, wz_[1], accz[r]);
                accz[r] = fmaf(s4.z, wz_[2], accz[r]);
                accz[r] = fmaf(s4.w, wz_[3], accz[r]);
                accn[r] = fmaf(s4.x, wn_[0], accn[r]);
                accn[r] = fmaf(s4.y, wn_[1], accn[r]);
                accn[r] = fmaf(s4.z, wn_[2], accn[r]);
                accn[r] = fmaf(s4.w, wn_[3], accn[r]);
            }
        }
        const float bxr = bx[j], bxz = bx[256 + j], bxn = bx[512 + j];
        float vals[16];
        #pragma unroll
        for (int r = 0; r < 16; ++r) {
            const int m = m0 + r;
            const int b = m & 1023;
            const float ghr = GhA[(size_t)b * 768 + j];
            const float ghz = GhA[(size_t)b * 768 + 256 + j];
            const float ghn = GhA[(size_t)b * 768 + 512 + j];
            const float rg = sigmf(accr[r] + bxr + ghr);
            const float zg = sigmf(accz[r] + bxz + ghz);
            const float ng = tanhf(accn[r] + bxn + rg * ghn);
            vals[r] = (1.f - zg) * ng + zg * ha[(size_t)b * 256 + j];
        }
        // fragment-packed store: frag = (m0>>4)*16 + (j>>4)
        const size_t fb = ((size_t)(m0 >> 4) * 16 + (j >> 4)) * 256;
        #pragma unroll
        for (int g = 0; g < 4; ++g) {
            ushort4 st;
            st.x = f2h(vals[4 * g + 0]);
            st.y = f2h(vals[4 * g + 1]);
            st.z = f2h(vals[4 * g + 2]);
            st.w = f2h(vals[4 * g + 3]);
            *(ushort4*)(ApfP + fb + ((size_t)((j & 15) + (g << 4)) << 2)) = st;
        }
    }
}

// ---------------------------------------------------------------------------
// Fraternal GRU fused MFMA (fp16): h = first-child hidden (slots 2p),
// x = first-child softmax (fp16+pad). 3 gates on a 64-col slab.
// 4 h-steps + 1 x-step; counted-vmcnt dbuf pipeline.
// hv (epilogue h values) grabbed from LDS during K-step sc = col0>>6.
// Apf read fragment-packed (ushort4, coalesced). Epilogue writes fp16 Ap2.
// ---------------------------------------------------------------------------
template<int BM>
__global__ __launch_bounds__(256) void gru_s_fused(
    const unsigned short* __restrict__ Hn2, const unsigned short* __restrict__ SP2n,
    const unsigned short* __restrict__ gsW2, const unsigned short* __restrict__ gsX2,
    const float* __restrict__ gs_bx, const float* __restrict__ gs_bh,
    const unsigned short* __restrict__ ApfP, unsigned short* __restrict__ Ap2)
{
    constexpr int MF = BM / 32;
    constexpr int AI = BM / 32;
    constexpr int ASZ = BM * 64;
    __shared__ __attribute__((aligned(16))) unsigned short As[2 * ASZ];
    __shared__ __attribute__((aligned(16))) unsigned short Ws[2 * 12288];  // 192x64

    const int tid = threadIdx.x;
    const int w = tid >> 6, lane = tid & 63;
    const int col0 = blockIdx.y * 64;
    const int m0 = blockIdx.x * BM;
    const int p = m0 >> 10;
    const size_t aBase = (((size_t)(2 * p)) << 10) + (m0 & 1023);
    const int wr = w >> 1, wc = w & 1;
    const int sc = col0 >> 6;   // K-step whose A-tile holds our epilogue hv cols

    f32x4 a_sr[MF][2] = {}, a_sz[MF][2] = {}, a_snh[MF][2] = {}, a_snx[MF][2] = {};
    unsigned short hvv[MF][2][4];

    auto stage = [&](int buf, int s) {
        #pragma unroll
        for (int i = 0; i < AI; ++i) {
            const int r = w * (BM / 4) + (i << 3) + (lane >> 3);
            const int sl = (lane & 7) ^ (r & 7);
            const unsigned short* src;
            if (s < 4) src = Hn2 + (aBase + r) * 256 + (s << 6) + (sl << 3);
            else       src = SP2n + (aBase + r) * 64 + (sl << 3);
            glds16(src, &As[buf * ASZ + ((w * (BM / 4) + (i << 3)) << 6)]);
        }
        #pragma unroll
        for (int j = 0; j < 6; ++j) {
            const int R = w * 48 + (j << 3) + (lane >> 3);
            const int g = R >> 6, c = R & 63;
            const int sl = (lane & 7) ^ (R & 7);
            const size_t grow = (size_t)(g * 256 + col0 + c);
            const unsigned short* src;
            if (s < 4) src = gsW2 + grow * 256 + (s << 6) + (sl << 3);
            else       src = gsX2 + grow * 64 + (sl << 3);
            glds16(src, &Ws[buf * 12288 + ((w * 48 + (j << 3)) << 6)]);
        }
    };

    auto compute = [&](int buf, bool dohv, f32x4 (*tr)[2], f32x4 (*tz)[2], f32x4 (*tn)[2]) {
        if (dohv) {
            // grab epilogue h values from the staged A-tile (cols col0..col0+63)
            #pragma unroll
            for (int mf = 0; mf < MF; ++mf)
                #pragma unroll
                for (int nf = 0; nf < 2; ++nf)
                    #pragma unroll
                    for (int r = 0; r < 4; ++r) {
                        const int row = wr * (BM / 2) + (mf << 4) + ((lane >> 4) << 2) + r;
                        const int jcl = (wc << 5) + (nf << 4) + (lane & 15);
                        hvv[mf][nf][r] =
                            As[buf * ASZ + (row << 6) + (((jcl >> 3) ^ (row & 7)) << 3) + (jcl & 7)];
                    }
        }
        #pragma unroll
        for (int kk = 0; kk < 2; ++kk) {
            f16x8 af[MF], bw[3][2];
            #pragma unroll
            for (int mf = 0; mf < MF; ++mf) {
                const int row = wr * (BM / 2) + (mf << 4) + (lane & 15);
                const int sl = (((kk << 2) | (lane >> 4)) ^ (row & 7)) << 3;
                af[mf] = *(const f16x8*)&As[buf * ASZ + (row << 6) + sl];
            }
            #pragma unroll
            for (int g = 0; g < 3; ++g)
                #pragma unroll
                for (int nf = 0; nf < 2; ++nf) {
                    const int R = (g << 6) + (wc << 5) + (nf << 4) + (lane & 15);
                    const int sl = (((kk << 2) | (lane >> 4)) ^ (R & 7)) << 3;
                    bw[g][nf] = *(const f16x8*)&Ws[buf * 12288 + (R << 6) + sl];
                }
            __builtin_amdgcn_s_setprio(1);
            #pragma unroll
            for (int mf = 0; mf < MF; ++mf)
                #pragma unroll
                for (int nf = 0; nf < 2; ++nf) {
                    tr[mf][nf] = __builtin_amdgcn_mfma_f32_16x16x32_f16(af[mf], bw[0][nf], tr[mf][nf], 0, 0, 0);
                    tz[mf][nf] = __builtin_amdgcn_mfma_f32_16x16x32_f16(af[mf], bw[1][nf], tz[mf][nf], 0, 0, 0);
                    tn[mf][nf] = __builtin_amdgcn_mfma_f32_16x16x32_f16(af[mf], bw[2][nf], tn[mf][nf], 0, 0, 0);
                }
            __builtin_amdgcn_s_setprio(0);
        }
    };

    stage(0, 0);
    #pragma unroll
    for (int s = 0; s < 5; ++s) {
        if (s + 1 < 5) { stage((s + 1) & 1, s + 1); vmwait<AI + 6>(); }
        else           { vmwait<0>(); }
        sbar();
        if (s < 4) compute(s & 1, s == sc, a_sr, a_sz, a_snh);
        else       compute(s & 1, false, a_sr, a_sz, a_snx);
        sbar();
    }

    #pragma unroll
    for (int nf = 0; nf < 2; ++nf) {
        const int jc = col0 + (wc << 5) + (nf << 4) + (lane & 15);
        const int jt = (col0 >> 4) + (wc << 1) + nf;
        const float bsr  = gs_bx[jc] + gs_bh[jc];
        const float bsz  = gs_bx[256 + jc] + gs_bh[256 + jc];
        const float bsnx = gs_bx[512 + jc];
        const float bsnh = gs_bh[512 + jc];
        #pragma unroll
        for (int mf = 0; mf < MF; ++mf) {
            const int gmt = (m0 >> 4) + wr * (BM / 32) + mf;
            const ushort4 av = *(const ushort4*)(ApfP + ((size_t)gmt * 16 + jt) * 256 + (lane << 2));
            const unsigned short apv[4] = {av.x, av.y, av.z, av.w};
            #pragma unroll
            for (int r = 0; r < 4; ++r) {
                const int rowl = wr * (BM / 2) + (mf << 4) + ((lane >> 4) << 2) + r;
                const int m = m0 + rowl;
                const float rs = sigmf(a_sr[mf][nf][r] + bsr);
                const float zs = sigmf(a_sz[mf][nf][r] + bsz);
                const float ns = tanhf(a_snx[mf][nf][r] + bsnx + rs * (a_snh[mf][nf][r] + bsnh));
                const float hv = h2f(hvv[mf][nf][r]);
                const float val = (1.f - zs) * ns + zs * hv + h2f(apv[r]);
                Ap2[(size_t)m * 256 + jc] = f2h(val);
            }
        }
    }
}

// ---------------------------------------------------------------------------
extern "C" void kernel_launch(void* const* d_in, const int* in_sizes, int n_in,
                              void* d_out, int out_size, void* d_ws, size_t ws_size,
                              hipStream_t stream) {
    (void)in_sizes; (void)n_in; (void)out_size;

    const float* z      = (const float*)d_in[0];
    const float* h2o_w  = (const float*)d_in[1];
    const float* h2o_b  = (const float*)d_in[2];
    const float* w_c_w  = (const float*)d_in[3];
    const float* w_c_b  = (const float*)d_in[4];
    const float* w_d_w  = (const float*)d_in[5];
    const float* w_d_b  = (const float*)d_in[6];
    const float* z2h1_w = (const float*)d_in[7];
    const float* z2h1_b = (const float*)d_in[8];
    const float* z2h2_w = (const float*)d_in[9];
    const float* z2h2_b = (const float*)d_in[10];
    const float* ga_wx  = (const float*)d_in[11];
    const float* ga_wh  = (const float*)d_in[12];
    const float* ga_bx  = (const float*)d_in[13];
    const float* ga_bh  = (const float*)d_in[14];
    const float* gs_wx  = (const float*)d_in[15];
    const float* gs_wh  = (const float*)d_in[16];
    const float* gs_bx  = (const float*)d_in[17];
    const float* gs_bh  = (const float*)d_in[18];

    float* out = (float*)d_out;

    size_t off = 0;
    auto alloc = [&](size_t bytes) -> void* {
        void* r = (char*)d_ws + off;
        off += (bytes + 255) & ~(size_t)255;
        return r;
    };
    unsigned short* H2a  = (unsigned short*)alloc(16ull * 1024 * 256 * 2);
    unsigned short* H2b  = (unsigned short*)alloc(32ull * 1024 * 256 * 2);
    unsigned short* SP2a = (unsigned short*)alloc(16ull * 1024 * 64 * 2);
    unsigned short* SP2b = (unsigned short*)alloc(32ull * 1024 * 64 * 2);
    float* hacF0 = (float*)alloc(1024ull * 256 * 4);
    float* hacF1 = (float*)alloc(1024ull * 256 * 4);
    unsigned short* hac20 = (unsigned short*)alloc(1024ull * 256 * 2);
    unsigned short* hac21 = (unsigned short*)alloc(1024ull * 256 * 2);
    float* GhA = (float*)alloc(1024ull * 768 * 4);
    unsigned short* ApfP = (unsigned short*)alloc(16ull * 1024 * 256 * 2); // frag-packed
    unsigned short* Ap2 = (unsigned short*)alloc(16ull * 1024 * 256 * 2);
    unsigned short* z2  = (unsigned short*)alloc(1024ull * 256 * 2);
    unsigned short* wd2 = (unsigned short*)alloc(256ull * 256 * 2);
    unsigned short* wc2 = (unsigned short*)alloc(256ull * 256 * 2);
    unsigned short* z12 = (unsigned short*)alloc(256ull * 256 * 2);
    unsigned short* z22 = (unsigned short*)alloc(256ull * 256 * 2);
    unsigned short* gaW2 = (unsigned short*)alloc(768ull * 256 * 2);
    unsigned short* gsW2 = (unsigned short*)alloc(768ull * 256 * 2);
    unsigned short* gsX2 = (unsigned short*)alloc(768ull * 64 * 2);
    unsigned short* h2o2 = (unsigned short*)alloc(32ull * 256 * 2);
    float* gaT = (float*)alloc(768ull * 32 * 4);   // transposed ga_wx [3][32][256]
    if (off > ws_size) return;  // tripwire: output stays poisoned -> visible fail

    const dim3 blk(256);

    CvtArgs ca = {{
        { z,      z2,   1024 * 256, 8, 0 },
        { w_d_w,  wd2,  256 * 256,  8, 0 },
        { w_c_w,  wc2,  256 * 256,  8, 0 },
        { z2h1_w, z12,  256 * 256,  8, 0 },
        { z2h2_w, z22,  256 * 256,  8, 0 },
        { ga_wh,  gaW2, 768 * 256,  8, 0 },
        { gs_wh,  gsW2, 768 * 256,  8, 0 },
        { gs_wx,  gsX2, 768 * 32,   5, 1 },
        { h2o_w,  h2o2, 32 * 256,   8, 0 },
        { ga_wx,  (unsigned short*)gaT, 768 * 32, 5, 2 },
    }};
    cvt_f16<<<dim3(64, 10), blk, 0, stream>>>(ca);

    // init: hac = z@z2h1^T+b ; H(root) = z@z2h2^T+b  (one multi dispatch)
    {
        GMulti gi;
        gi.d[0] = { z2, z12, z2h1_b, hacF0, 256, hac20, 1, 0, 16 };
        gi.d[1] = { z2, z22, z2h2_b, nullptr, 0, H2a, 1, 0, 16 };
        gi.d[2] = gi.d[1];
        gi.n0 = 32; gi.n01 = 64;
        mfma_gemm_multi<64><<<dim3(64), blk, 0, stream>>>(gi);
    }
    pred_mfma_grua<<<dim3(8), blk, 0, stream>>>(H2a, h2o2, h2o_b, out, SP2a, 0, 1, 0,
                                                8, nullptr, nullptr, nullptr, nullptr,
                                                nullptr, nullptr);

    unsigned short* cur2 = H2a;  unsigned short* nxt2 = H2b;
    unsigned short* spc  = SP2a; unsigned short* spn  = SP2b;
    float* hf = hacF0;  float* hn = hacF1;
    unsigned short* hf2 = hac20; unsigned short* hn2 = hac21;

    for (int l = 0; l < DEPTHC - 1; ++l) {
        const int M = (1 << l) * Bdim;
        const bool small = (M <= 8192);
        const int BMv = small ? 64 : 128;
        const int nbm = M / BMv;
        const int nbh = 1024 / BMv;   // m-tiles for the 1024-row GEMMs

        // D1: lin_d(first) || GhA || lin_c  (independent; one dispatch)
        {
            GMulti g1;
            g1.d[0] = { cur2, wd2, w_d_b, nullptr, 0, nxt2, 2, 0, nbm };
            g1.d[1] = { hf2, gaW2, ga_bh, GhA, 768, nullptr, 1, 0, nbh };
            g1.d[2] = { hf2, wc2, w_c_b, hn, 256, hn2, 1, 0, nbh };
            const int nb0 = nbm * 2, nb1 = nbh * 6;
            const int nb2 = (l < DEPTHC - 2) ? nbh * 2 : 0;
            g1.n0 = nb0; g1.n01 = nb0 + nb1;
            const int ntot = nb0 + nb1 + nb2;
            if (small) mfma_gemm_multi<64><<<dim3(ntot), blk, 0, stream>>>(g1);
            else       mfma_gemm_multi<128><<<dim3(ntot), blk, 0, stream>>>(g1);
        }
        // D2: pred(first children) || gru_a
        pred_mfma_grua<<<dim3(M / 128 + M / 16), blk, 0, stream>>>(
            nxt2, h2o2, h2o_b, out, spn, l + 1, 2, 0, M / 128,
            spc, GhA, gaT, ga_bx, hf, ApfP);
        // D3: fraternal GRU + combine -> hidden2 (fp16) in Ap2
        if (small) gru_s_fused<64><<<dim3(M / 64, 4), blk, 0, stream>>>(nxt2, spn, gsW2, gsX2, gs_bx, gs_bh, ApfP, Ap2);
        else       gru_s_fused<128><<<dim3(M / 128, 4), blk, 0, stream>>>(nxt2, spn, gsW2, gsX2, gs_bx, gs_bh, ApfP, Ap2);
        // D4: lin_d(second children)
        if (small) mfma_gemm<64><<<dim3(M / 64, 2), blk, 0, stream>>>(Ap2, wd2, w_d_b, nullptr, 0, nxt2, 2, 1);
        else       mfma_gemm<128><<<dim3(M / 128, 2), blk, 0, stream>>>(Ap2, wd2, w_d_b, nullptr, 0, nxt2, 2, 1);
        // D5: pred(second children)
        pred_mfma_grua<<<dim3(M / 128), blk, 0, stream>>>(
            nxt2, h2o2, h2o_b, out, spn, l + 1, 2, 1, M / 128,
            nullptr, nullptr, nullptr, nullptr, nullptr, nullptr);

        // swap ping-pong buffers
        unsigned short* t2;
        t2 = cur2; cur2 = nxt2; nxt2 = t2;
        t2 = spc;  spc  = spn;  spn  = t2;
        float* tf = hf; hf = hn; hn = tf;
        t2 = hf2; hf2 = hn2; hn2 = t2;
    }
}

// Round 13
// 419.498 us; speedup vs baseline: 1.7982x; 1.7982x over previous
//
#include <hip/hip_runtime.h>
#include <math.h>

// Problem constants (fixed by the reference)
#define Bdim 1024
#define DEPTHC 6

typedef __attribute__((ext_vector_type(8))) _Float16 f16x8;
typedef __attribute__((ext_vector_type(4))) float f32x4;

__device__ __forceinline__ unsigned short f2h(float x) {
    _Float16 h = (_Float16)x;
    unsigned short u;
    __builtin_memcpy(&u, &h, 2);
    return u;
}
__device__ __forceinline__ float h2f(unsigned short u) {
    _Float16 h;
    __builtin_memcpy(&h, &u, 2);
    return (float)h;
}
__device__ __forceinline__ float sigmf(float x) { return 1.0f / (1.0f + expf(-x)); }

__device__ __forceinline__ void glds16(const void* g, void* l) {
    __builtin_amdgcn_global_load_lds(
        (const __attribute__((address_space(1))) unsigned int*)g,
        (__attribute__((address_space(3))) unsigned int*)l, 16, 0, 0);
}

// raw barrier (no implicit vmcnt drain) + counted vmcnt waits
__device__ __forceinline__ void sbar() { asm volatile("s_barrier" ::: "memory"); }
template<int N> __device__ __forceinline__ void vmwait() {
    static_assert(N == 0 || N == 4 || N == 6 || N == 8 || N == 10, "unsupported vmcnt");
    if constexpr (N == 0)  asm volatile("s_waitcnt vmcnt(0)" ::: "memory");
    if constexpr (N == 4)  asm volatile("s_waitcnt vmcnt(4)" ::: "memory");
    if constexpr (N == 6)  asm volatile("s_waitcnt vmcnt(6)" ::: "memory");
    if constexpr (N == 8)  asm volatile("s_waitcnt vmcnt(8)" ::: "memory");
    if constexpr (N == 10) asm volatile("s_waitcnt vmcnt(10)" ::: "memory");
    __builtin_amdgcn_sched_barrier(0);
}

// Preorder index of node (level, q) in a full binary tree of depth DEPTHC.
__device__ __forceinline__ int preorder_idx(int level, int q) {
    int idx = 0, rem = DEPTHC;
    for (int k = level - 1; k >= 0; --k) {
        int b = (q >> k) & 1;
        idx += 1 + b * ((1 << (rem - 1)) - 1);
        rem--;
    }
    return idx;
}

// ---------------------------------------------------------------------------
// fp32 -> fp16 converter. mode=0: dst[r*k+c]. mode=1: dst[r*2k+c]=v, zero pad.
// mode=2: fp32->fp32 TRANSPOSE of ga_wx [3][256][32] -> gaT [3][32][256].
// ---------------------------------------------------------------------------
struct CvtEnt { const float* src; unsigned short* dst; int n; int klog2; int mode; };
struct CvtArgs { CvtEnt e[10]; };

__global__ __launch_bounds__(256) void cvt_f16(CvtArgs a) {
    CvtEnt E = a.e[blockIdx.y];
    const int k = 1 << E.klog2;
    for (int t = blockIdx.x * 256 + threadIdx.x; t < E.n; t += gridDim.x * 256) {
        const float x = E.src[t];
        if (E.mode == 0) {
            const int r = t >> E.klog2, c = t & (k - 1);
            E.dst[(size_t)r * k + c] = f2h(x);
        } else if (E.mode == 1) {
            const int r = t >> E.klog2, c = t & (k - 1);
            E.dst[(size_t)r * 2 * k + c] = f2h(x);
            E.dst[(size_t)r * 2 * k + k + c] = 0;
        } else {
            // transpose [3][256][32] -> [3][32][256], fp32
            float* df = (float*)E.dst;
            const int g = t >> 13, rem = t & 8191;
            const int j = rem >> 5, kk = rem & 31;
            df[(g << 13) + (kk << 8) + j] = x;
        }
    }
}

// ---------------------------------------------------------------------------
// fp16 MFMA GEMM body: C = A @ W^T + bias, K=256, 4 K-steps of BK=64.
// Tile BM x 128, 4 waves. Counted-vmcnt double-buffered pipeline.
// ---------------------------------------------------------------------------
template<int BM>
__device__ __forceinline__ void gemm_body(
    int m0, int col0,
    const unsigned short* __restrict__ A2, const unsigned short* __restrict__ W2,
    const float* __restrict__ bias, float* __restrict__ Cf, int Nf,
    unsigned short* __restrict__ C2, int outStride, int outOffset,
    unsigned short* As, unsigned short* Ws)
{
    constexpr int MF = BM / 32;
    constexpr int AI = BM / 32;
    constexpr int ASZ = BM * 64;

    const int tid = threadIdx.x;
    const int w = tid >> 6, lane = tid & 63;
    const int p = m0 >> 10;
    const int wm = (w >> 1) * (BM / 2), wn = (w & 1) << 6;

    f32x4 acc[MF][4] = {};

    auto stage = [&](int buf, int s) {
        const int ka = s << 6;
        #pragma unroll
        for (int i = 0; i < AI; ++i) {
            const int r = w * (BM / 4) + (i << 3) + (lane >> 3);
            const int sl = (lane & 7) ^ (r & 7);
            glds16(A2 + (size_t)(m0 + r) * 256 + ka + (sl << 3),
                   &As[buf * ASZ + ((w * (BM / 4) + (i << 3)) << 6)]);
        }
        #pragma unroll
        for (int i = 0; i < 4; ++i) {
            const int r = (w << 5) + (i << 3) + (lane >> 3);
            const int sl = (lane & 7) ^ (r & 7);
            glds16(W2 + (size_t)(col0 + r) * 256 + ka + (sl << 3),
                   &Ws[buf * 8192 + (w << 11) + (i << 9)]);
        }
    };
    auto compute = [&](int buf) {
        #pragma unroll
        for (int kk = 0; kk < 2; ++kk) {
            f16x8 af[MF], bw[4];
            #pragma unroll
            for (int mf = 0; mf < MF; ++mf) {
                const int row = wm + (mf << 4) + (lane & 15);
                const int sl = (((kk << 2) | (lane >> 4)) ^ (row & 7)) << 3;
                af[mf] = *(const f16x8*)&As[buf * ASZ + (row << 6) + sl];
            }
            #pragma unroll
            for (int nf = 0; nf < 4; ++nf) {
                const int row = wn + (nf << 4) + (lane & 15);
                const int sl = (((kk << 2) | (lane >> 4)) ^ (row & 7)) << 3;
                bw[nf] = *(const f16x8*)&Ws[buf * 8192 + (row << 6) + sl];
            }
            __builtin_amdgcn_s_setprio(1);
            #pragma unroll
            for (int mf = 0; mf < MF; ++mf)
                #pragma unroll
                for (int nf = 0; nf < 4; ++nf)
                    acc[mf][nf] = __builtin_amdgcn_mfma_f32_16x16x32_f16(
                        af[mf], bw[nf], acc[mf][nf], 0, 0, 0);
            __builtin_amdgcn_s_setprio(0);
        }
    };

    stage(0, 0);
    #pragma unroll
    for (int s = 0; s < 4; ++s) {
        if (s + 1 < 4) { stage((s + 1) & 1, s + 1); vmwait<AI + 4>(); }
        else           { vmwait<0>(); }
        sbar();
        compute(s & 1);
        sbar();
    }

    const size_t oBase = (((size_t)(p * outStride + outOffset)) << 10) + (m0 & 1023);
    #pragma unroll
    for (int nf = 0; nf < 4; ++nf) {
        const int col = col0 + wn + (nf << 4) + (lane & 15);
        const float bj = bias[col];
        #pragma unroll
        for (int mf = 0; mf < MF; ++mf) {
            const int rb = wm + (mf << 4) + ((lane >> 4) << 2);
            #pragma unroll
            for (int r = 0; r < 4; ++r) {
                const float v = acc[mf][nf][r] + bj;
                const size_t orow = oBase + rb + r;
                if (Cf) Cf[orow * (size_t)Nf + col] = v;
                if (C2) C2[orow * 256 + col] = f2h(v);
            }
        }
    }
}

template<int BM>
__global__ __launch_bounds__(256) void mfma_gemm(
    const unsigned short* __restrict__ A2, const unsigned short* __restrict__ W2,
    const float* __restrict__ bias, float* __restrict__ Cf, int Nf,
    unsigned short* __restrict__ C2, int outStride, int outOffset)
{
    __shared__ __attribute__((aligned(16))) unsigned short As[2 * BM * 64];
    __shared__ __attribute__((aligned(16))) unsigned short Ws[2 * 8192];
    gemm_body<BM>(blockIdx.x * BM, blockIdx.y * 128, A2, W2, bias, Cf, Nf, C2,
                  outStride, outOffset, As, Ws);
}

// Multi-GEMM: up to 3 independent GEMMs in one dispatch (flattened 1D grid).
struct GDesc {
    const unsigned short* A; const unsigned short* W; const float* bias;
    float* Cf; int Nf; unsigned short* C2; int outStride; int outOffset; int nbm;
};
struct GMulti { GDesc d[3]; int n0; int n01; };

template<int BM>
__global__ __launch_bounds__(256) void mfma_gemm_multi(GMulti g) {
    __shared__ __attribute__((aligned(16))) unsigned short As[2 * BM * 64];
    __shared__ __attribute__((aligned(16))) unsigned short Ws[2 * 8192];
    const int id = blockIdx.x;
    int di, base;
    if (id < g.n0)       { di = 0; base = 0; }
    else if (id < g.n01) { di = 1; base = g.n0; }
    else                 { di = 2; base = g.n01; }
    const GDesc D = g.d[di];
    const int lid = id - base;
    gemm_body<BM>((lid % D.nbm) * BM, (lid / D.nbm) * 128, D.A, D.W, D.bias,
                  D.Cf, D.Nf, D.C2, D.outStride, D.outOffset, As, Ws);
}

// ---------------------------------------------------------------------------
// MFMA pred + softmax (+ optional gru_a), block-partitioned.
// pred blocks [0,npred): BM=128 rows, 4 waves x 32 rows x 32 cols.
// gru_a blocks [npred,...): x-dots K=32 with TRANSPOSED gaT [3][32][256]
//   (coalesced, unroll-limited to avoid VGPR blowup), sps in LDS [16][36]
//   read as float4; h-parts from GhA; frag-packed fp16 output ApfP.
// ---------------------------------------------------------------------------
__global__ __launch_bounds__(256) void pred_mfma_grua(
    const unsigned short* __restrict__ H2, const unsigned short* __restrict__ h2o2,
    const float* __restrict__ h2o_b, float* __restrict__ out,
    unsigned short* __restrict__ SP2, int level, int nodeStride, int nodeOffset,
    int npred,
    const unsigned short* __restrict__ SP2c, const float* __restrict__ GhA,
    const float* __restrict__ gaT, const float* __restrict__ bx,
    const float* __restrict__ ha, unsigned short* __restrict__ ApfP)
{
    __shared__ __attribute__((aligned(16))) unsigned short As[2 * 8192];   // 2 x 128x64
    __shared__ __attribute__((aligned(16))) unsigned short Wsm[8192];      // 4 steps x 32x64

    const int tid = threadIdx.x;
    const int w = tid >> 6, lane = tid & 63;

    if ((int)blockIdx.x < npred) {
        const int m0g = blockIdx.x * 128;
        const int p = m0g >> 10;
        const int q = p * nodeStride + nodeOffset;
        const int b0 = m0g & 1023;
        const size_t aBase = ((size_t)q << 10) + b0;

        // one-time weight stage: wave w stages its K-step w (32 rows x 64)
        #pragma unroll
        for (int i = 0; i < 4; ++i) {
            const int r = (i << 3) + (lane >> 3);
            const int sl = (lane & 7) ^ (r & 7);
            glds16(h2o2 + (size_t)r * 256 + (w << 6) + (sl << 3),
                   &Wsm[(w << 11) + (i << 9)]);
        }

        auto stageA = [&](int buf, int s) {
            #pragma unroll
            for (int i = 0; i < 4; ++i) {
                const int r = (w << 5) + (i << 3) + (lane >> 3);
                const int sl = (lane & 7) ^ (r & 7);
                glds16(H2 + (aBase + r) * 256 + (s << 6) + (sl << 3),
                       &As[buf * 8192 + (((w << 5) + (i << 3)) << 6)]);
            }
        };

        f32x4 acc[2][2] = {};

        auto compute = [&](int buf, int s) {
            #pragma unroll
            for (int kk = 0; kk < 2; ++kk) {
                f16x8 af[2], bw[2];
                #pragma unroll
                for (int mf = 0; mf < 2; ++mf) {
                    const int row = (w << 5) + (mf << 4) + (lane & 15);
                    const int sl = (((kk << 2) | (lane >> 4)) ^ (row & 7)) << 3;
                    af[mf] = *(const f16x8*)&As[buf * 8192 + (row << 6) + sl];
                }
                #pragma unroll
                for (int nf = 0; nf < 2; ++nf) {
                    const int rowb = (nf << 4) + (lane & 15);
                    const int sl = (((kk << 2) | (lane >> 4)) ^ (rowb & 7)) << 3;
                    bw[nf] = *(const f16x8*)&Wsm[(s << 11) + (rowb << 6) + sl];
                }
                __builtin_amdgcn_s_setprio(1);
                #pragma unroll
                for (int mf = 0; mf < 2; ++mf)
                    #pragma unroll
                    for (int nf = 0; nf < 2; ++nf)
                        acc[mf][nf] = __builtin_amdgcn_mfma_f32_16x16x32_f16(
                            af[mf], bw[nf], acc[mf][nf], 0, 0, 0);
                __builtin_amdgcn_s_setprio(0);
            }
        };

        stageA(0, 0);
        #pragma unroll
        for (int s = 0; s < 4; ++s) {
            if (s + 1 < 4) { stageA((s + 1) & 1, s + 1); vmwait<4>(); }
            else           { vmwait<0>(); }
            sbar();
            compute(s & 1, s);
            sbar();
        }

        const int idx = preorder_idx(level, q);
        const int colb = lane & 15;
        const float bj0 = h2o_b[colb];
        const float bj1 = h2o_b[16 + colb];

        #pragma unroll
        for (int mf = 0; mf < 2; ++mf) {
            #pragma unroll
            for (int r = 0; r < 4; ++r) {
                const int rowl = (w << 5) + (mf << 4) + ((lane >> 4) << 2) + r;
                const int b = b0 + rowl;
                const float v0 = acc[mf][0][r] + bj0;
                const float v1 = acc[mf][1][r] + bj1;
                const size_t obase = (((size_t)idx << 10) + b) * 32;
                out[obase + colb] = v0;
                out[obase + 16 + colb] = v1;
                float mx = fmaxf(v0, v1);
                #pragma unroll
                for (int off = 8; off > 0; off >>= 1) mx = fmaxf(mx, __shfl_xor(mx, off, 16));
                const float e0 = expf(v0 - mx), e1 = expf(v1 - mx);
                float sum = e0 + e1;
                #pragma unroll
                for (int off = 8; off > 0; off >>= 1) sum += __shfl_xor(sum, off, 16);
                const float inv = 1.0f / sum;
                const size_t sbase = (((size_t)q << 10) + b) * 64;
                SP2[sbase + colb] = f2h(e0 * inv);
                SP2[sbase + 16 + colb] = f2h(e1 * inv);
                SP2[sbase + 32 + colb] = 0;
                SP2[sbase + 48 + colb] = 0;
            }
        }
    } else {
        // gru_a part: transposed coalesced gaT reads + float4 sps broadcasts.
        // NOTE: unroll 1 on the k4 loop — full unroll hoists 96 global loads
        // into registers (VGPR 256 + scratch spill, r12 regression).
        float (*sps)[36] = (float(*)[36])As;    // 16*36*4 = 2304 B
        const int bid = blockIdx.x - npred;
        const int m0  = bid * 16;

        for (int t = tid; t < 16 * 32; t += 256) {
            const int r = t >> 5, k = t & 31;
            sps[r][k] = h2f(SP2c[((size_t)(m0 + r)) * 64 + k]);
        }
        __syncthreads();

        const int j = tid;
        float accr[16] = {}, accz[16] = {}, accn[16] = {};
        #pragma unroll 1
        for (int k4 = 0; k4 < 32; k4 += 4) {
            float wr_[4], wz_[4], wn_[4];
            #pragma unroll
            for (int u = 0; u < 4; ++u) {
                wr_[u] = gaT[(k4 + u) * 256 + j];
                wz_[u] = gaT[8192 + (k4 + u) * 256 + j];
                wn_[u] = gaT[16384 + (k4 + u) * 256 + j];
            }
            #pragma unroll
            for (int r = 0; r < 16; ++r) {
                const float4 s4 = *(const float4*)&sps[r][k4];
                accr[r] = fmaf(s4.x, wr_[0], accr[r]);
                accr[r] = fmaf(s4.y, wr_[1], accr[r]);
                accr[r] = fmaf(s4.z, wr_[2], accr[r]);
                accr[r] = fmaf(s4.w, wr_[3], accr[r]);
                accz[r] = fmaf(s4.x, wz_[0], accz[r]);
                accz[r] = fmaf(s4.y, wz_[1], accz[r]);
                accz[r] = fmaf(s4.z, wz_[2], accz[r]);
                accz[r] = fmaf(s4.w, wz_[3], accz[r]);
                accn[r] = fmaf(s4.x, wn_[0], accn[r]);
                accn[r] = fmaf(s4.y, wn_[1], accn[r]);
                accn[r] = fmaf(s4.z, wn_[2], accn[r]);
                accn[r] = fmaf(s4.w, wn_[3], accn[r]);
            }
        }
        const float bxr = bx[j], bxz = bx[256 + j], bxn = bx[512 + j];
        float vals[16];
        #pragma unroll
        for (int r = 0; r < 16; ++r) {
            const int m = m0 + r;
            const int b = m & 1023;
            const float ghr = GhA[(size_t)b * 768 + j];
            const float ghz = GhA[(size_t)b * 768 + 256 + j];
            const float ghn = GhA[(size_t)b * 768 + 512 + j];
            const float rg = sigmf(accr[r] + bxr + ghr);
            const float zg = sigmf(accz[r] + bxz + ghz);
            const float ng = tanhf(accn[r] + bxn + rg * ghn);
            vals[r] = (1.f - zg) * ng + zg * ha[(size_t)b * 256 + j];
        }
        // fragment-packed store: frag = (m0>>4)*16 + (j>>4)
        const size_t fb = ((size_t)(m0 >> 4) * 16 + (j >> 4)) * 256;
        #pragma unroll
        for (int g = 0; g < 4; ++g) {
            ushort4 st;
            st.x = f2h(vals[4 * g + 0]);
            st.y = f2h(vals[4 * g + 1]);
            st.z = f2h(vals[4 * g + 2]);
            st.w = f2h(vals[4 * g + 3]);
            *(ushort4*)(ApfP + fb + ((size_t)((j & 15) + (g << 4)) << 2)) = st;
        }
    }
}

// ---------------------------------------------------------------------------
// Fraternal GRU fused MFMA (fp16): h = first-child hidden (slots 2p),
// x = first-child softmax (fp16+pad). 3 gates on a 64-col slab.
// 4 h-steps + 1 x-step; counted-vmcnt dbuf pipeline.
// hv (epilogue h values) grabbed from LDS during K-step sc = col0>>6.
// Apf read fragment-packed (ushort4, coalesced). Epilogue writes fp16 Ap2.
// ---------------------------------------------------------------------------
template<int BM>
__global__ __launch_bounds__(256) void gru_s_fused(
    const unsigned short* __restrict__ Hn2, const unsigned short* __restrict__ SP2n,
    const unsigned short* __restrict__ gsW2, const unsigned short* __restrict__ gsX2,
    const float* __restrict__ gs_bx, const float* __restrict__ gs_bh,
    const unsigned short* __restrict__ ApfP, unsigned short* __restrict__ Ap2)
{
    constexpr int MF = BM / 32;
    constexpr int AI = BM / 32;
    constexpr int ASZ = BM * 64;
    __shared__ __attribute__((aligned(16))) unsigned short As[2 * ASZ];
    __shared__ __attribute__((aligned(16))) unsigned short Ws[2 * 12288];  // 192x64

    const int tid = threadIdx.x;
    const int w = tid >> 6, lane = tid & 63;
    const int col0 = blockIdx.y * 64;
    const int m0 = blockIdx.x * BM;
    const int p = m0 >> 10;
    const size_t aBase = (((size_t)(2 * p)) << 10) + (m0 & 1023);
    const int wr = w >> 1, wc = w & 1;
    const int sc = col0 >> 6;   // K-step whose A-tile holds our epilogue hv cols

    f32x4 a_sr[MF][2] = {}, a_sz[MF][2] = {}, a_snh[MF][2] = {}, a_snx[MF][2] = {};
    unsigned short hvv[MF][2][4];

    auto stage = [&](int buf, int s) {
        #pragma unroll
        for (int i = 0; i < AI; ++i) {
            const int r = w * (BM / 4) + (i << 3) + (lane >> 3);
            const int sl = (lane & 7) ^ (r & 7);
            const unsigned short* src;
            if (s < 4) src = Hn2 + (aBase + r) * 256 + (s << 6) + (sl << 3);
            else       src = SP2n + (aBase + r) * 64 + (sl << 3);
            glds16(src, &As[buf * ASZ + ((w * (BM / 4) + (i << 3)) << 6)]);
        }
        #pragma unroll
        for (int j = 0; j < 6; ++j) {
            const int R = w * 48 + (j << 3) + (lane >> 3);
            const int g = R >> 6, c = R & 63;
            const int sl = (lane & 7) ^ (R & 7);
            const size_t grow = (size_t)(g * 256 + col0 + c);
            const unsigned short* src;
            if (s < 4) src = gsW2 + grow * 256 + (s << 6) + (sl << 3);
            else       src = gsX2 + grow * 64 + (sl << 3);
            glds16(src, &Ws[buf * 12288 + ((w * 48 + (j << 3)) << 6)]);
        }
    };

    auto compute = [&](int buf, bool dohv, f32x4 (*tr)[2], f32x4 (*tz)[2], f32x4 (*tn)[2]) {
        if (dohv) {
            // grab epilogue h values from the staged A-tile (cols col0..col0+63)
            #pragma unroll
            for (int mf = 0; mf < MF; ++mf)
                #pragma unroll
                for (int nf = 0; nf < 2; ++nf)
                    #pragma unroll
                    for (int r = 0; r < 4; ++r) {
                        const int row = wr * (BM / 2) + (mf << 4) + ((lane >> 4) << 2) + r;
                        const int jcl = (wc << 5) + (nf << 4) + (lane & 15);
                        hvv[mf][nf][r] =
                            As[buf * ASZ + (row << 6) + (((jcl >> 3) ^ (row & 7)) << 3) + (jcl & 7)];
                    }
        }
        #pragma unroll
        for (int kk = 0; kk < 2; ++kk) {
            f16x8 af[MF], bw[3][2];
            #pragma unroll
            for (int mf = 0; mf < MF; ++mf) {
                const int row = wr * (BM / 2) + (mf << 4) + (lane & 15);
                const int sl = (((kk << 2) | (lane >> 4)) ^ (row & 7)) << 3;
                af[mf] = *(const f16x8*)&As[buf * ASZ + (row << 6) + sl];
            }
            #pragma unroll
            for (int g = 0; g < 3; ++g)
                #pragma unroll
                for (int nf = 0; nf < 2; ++nf) {
                    const int R = (g << 6) + (wc << 5) + (nf << 4) + (lane & 15);
                    const int sl = (((kk << 2) | (lane >> 4)) ^ (R & 7)) << 3;
                    bw[g][nf] = *(const f16x8*)&Ws[buf * 12288 + (R << 6) + sl];
                }
            __builtin_amdgcn_s_setprio(1);
            #pragma unroll
            for (int mf = 0; mf < MF; ++mf)
                #pragma unroll
                for (int nf = 0; nf < 2; ++nf) {
                    tr[mf][nf] = __builtin_amdgcn_mfma_f32_16x16x32_f16(af[mf], bw[0][nf], tr[mf][nf], 0, 0, 0);
                    tz[mf][nf] = __builtin_amdgcn_mfma_f32_16x16x32_f16(af[mf], bw[1][nf], tz[mf][nf], 0, 0, 0);
                    tn[mf][nf] = __builtin_amdgcn_mfma_f32_16x16x32_f16(af[mf], bw[2][nf], tn[mf][nf], 0, 0, 0);
                }
            __builtin_amdgcn_s_setprio(0);
        }
    };

    stage(0, 0);
    #pragma unroll
    for (int s = 0; s < 5; ++s) {
        if (s + 1 < 5) { stage((s + 1) & 1, s + 1); vmwait<AI + 6>(); }
        else           { vmwait<0>(); }
        sbar();
        if (s < 4) compute(s & 1, s == sc, a_sr, a_sz, a_snh);
        else       compute(s & 1, false, a_sr, a_sz, a_snx);
        sbar();
    }

    #pragma unroll
    for (int nf = 0; nf < 2; ++nf) {
        const int jc = col0 + (wc << 5) + (nf << 4) + (lane & 15);
        const int jt = (col0 >> 4) + (wc << 1) + nf;
        const float bsr  = gs_bx[jc] + gs_bh[jc];
        const float bsz  = gs_bx[256 + jc] + gs_bh[256 + jc];
        const float bsnx = gs_bx[512 + jc];
        const float bsnh = gs_bh[512 + jc];
        #pragma unroll
        for (int mf = 0; mf < MF; ++mf) {
            const int gmt = (m0 >> 4) + wr * (BM / 32) + mf;
            const ushort4 av = *(const ushort4*)(ApfP + ((size_t)gmt * 16 + jt) * 256 + (lane << 2));
            const unsigned short apv[4] = {av.x, av.y, av.z, av.w};
            #pragma unroll
            for (int r = 0; r < 4; ++r) {
                const int rowl = wr * (BM / 2) + (mf << 4) + ((lane >> 4) << 2) + r;
                const int m = m0 + rowl;
                const float rs = sigmf(a_sr[mf][nf][r] + bsr);
                const float zs = sigmf(a_sz[mf][nf][r] + bsz);
                const float ns = tanhf(a_snx[mf][nf][r] + bsnx + rs * (a_snh[mf][nf][r] + bsnh));
                const float hv = h2f(hvv[mf][nf][r]);
                const float val = (1.f - zs) * ns + zs * hv + h2f(apv[r]);
                Ap2[(size_t)m * 256 + jc] = f2h(val);
            }
        }
    }
}

// ---------------------------------------------------------------------------
extern "C" void kernel_launch(void* const* d_in, const int* in_sizes, int n_in,
                              void* d_out, int out_size, void* d_ws, size_t ws_size,
                              hipStream_t stream) {
    (void)in_sizes; (void)n_in; (void)out_size;

    const float* z      = (const float*)d_in[0];
    const float* h2o_w  = (const float*)d_in[1];
    const float* h2o_b  = (const float*)d_in[2];
    const float* w_c_w  = (const float*)d_in[3];
    const float* w_c_b  = (const float*)d_in[4];
    const float* w_d_w  = (const float*)d_in[5];
    const float* w_d_b  = (const float*)d_in[6];
    const float* z2h1_w = (const float*)d_in[7];
    const float* z2h1_b = (const float*)d_in[8];
    const float* z2h2_w = (const float*)d_in[9];
    const float* z2h2_b = (const float*)d_in[10];
    const float* ga_wx  = (const float*)d_in[11];
    const float* ga_wh  = (const float*)d_in[12];
    const float* ga_bx  = (const float*)d_in[13];
    const float* ga_bh  = (const float*)d_in[14];
    const float* gs_wx  = (const float*)d_in[15];
    const float* gs_wh  = (const float*)d_in[16];
    const float* gs_bx  = (const float*)d_in[17];
    const float* gs_bh  = (const float*)d_in[18];

    float* out = (float*)d_out;

    size_t off = 0;
    auto alloc = [&](size_t bytes) -> void* {
        void* r = (char*)d_ws + off;
        off += (bytes + 255) & ~(size_t)255;
        return r;
    };
    unsigned short* H2a  = (unsigned short*)alloc(16ull * 1024 * 256 * 2);
    unsigned short* H2b  = (unsigned short*)alloc(32ull * 1024 * 256 * 2);
    unsigned short* SP2a = (unsigned short*)alloc(16ull * 1024 * 64 * 2);
    unsigned short* SP2b = (unsigned short*)alloc(32ull * 1024 * 64 * 2);
    float* hacF0 = (float*)alloc(1024ull * 256 * 4);
    float* hacF1 = (float*)alloc(1024ull * 256 * 4);
    unsigned short* hac20 = (unsigned short*)alloc(1024ull * 256 * 2);
    unsigned short* hac21 = (unsigned short*)alloc(1024ull * 256 * 2);
    float* GhA = (float*)alloc(1024ull * 768 * 4);
    unsigned short* ApfP = (unsigned short*)alloc(16ull * 1024 * 256 * 2); // frag-packed
    unsigned short* Ap2 = (unsigned short*)alloc(16ull * 1024 * 256 * 2);
    unsigned short* z2  = (unsigned short*)alloc(1024ull * 256 * 2);
    unsigned short* wd2 = (unsigned short*)alloc(256ull * 256 * 2);
    unsigned short* wc2 = (unsigned short*)alloc(256ull * 256 * 2);
    unsigned short* z12 = (unsigned short*)alloc(256ull * 256 * 2);
    unsigned short* z22 = (unsigned short*)alloc(256ull * 256 * 2);
    unsigned short* gaW2 = (unsigned short*)alloc(768ull * 256 * 2);
    unsigned short* gsW2 = (unsigned short*)alloc(768ull * 256 * 2);
    unsigned short* gsX2 = (unsigned short*)alloc(768ull * 64 * 2);
    unsigned short* h2o2 = (unsigned short*)alloc(32ull * 256 * 2);
    float* gaT = (float*)alloc(768ull * 32 * 4);   // transposed ga_wx [3][32][256]
    if (off > ws_size) return;  // tripwire: output stays poisoned -> visible fail

    const dim3 blk(256);

    CvtArgs ca = {{
        { z,      z2,   1024 * 256, 8, 0 },
        { w_d_w,  wd2,  256 * 256,  8, 0 },
        { w_c_w,  wc2,  256 * 256,  8, 0 },
        { z2h1_w, z12,  256 * 256,  8, 0 },
        { z2h2_w, z22,  256 * 256,  8, 0 },
        { ga_wh,  gaW2, 768 * 256,  8, 0 },
        { gs_wh,  gsW2, 768 * 256,  8, 0 },
        { gs_wx,  gsX2, 768 * 32,   5, 1 },
        { h2o_w,  h2o2, 32 * 256,   8, 0 },
        { ga_wx,  (unsigned short*)gaT, 768 * 32, 5, 2 },
    }};
    cvt_f16<<<dim3(64, 10), blk, 0, stream>>>(ca);

    // init: hac = z@z2h1^T+b ; H(root) = z@z2h2^T+b  (one multi dispatch)
    {
        GMulti gi;
        gi.d[0] = { z2, z12, z2h1_b, hacF0, 256, hac20, 1, 0, 16 };
        gi.d[1] = { z2, z22, z2h2_b, nullptr, 0, H2a, 1, 0, 16 };
        gi.d[2] = gi.d[1];
        gi.n0 = 32; gi.n01 = 64;
        mfma_gemm_multi<64><<<dim3(64), blk, 0, stream>>>(gi);
    }
    pred_mfma_grua<<<dim3(8), blk, 0, stream>>>(H2a, h2o2, h2o_b, out, SP2a, 0, 1, 0,
                                                8, nullptr, nullptr, nullptr, nullptr,
                                                nullptr, nullptr);

    unsigned short* cur2 = H2a;  unsigned short* nxt2 = H2b;
    unsigned short* spc  = SP2a; unsigned short* spn  = SP2b;
    float* hf = hacF0;  float* hn = hacF1;
    unsigned short* hf2 = hac20; unsigned short* hn2 = hac21;

    for (int l = 0; l < DEPTHC - 1; ++l) {
        const int M = (1 << l) * Bdim;
        const bool small = (M <= 8192);
        const int BMv = small ? 64 : 128;
        const int nbm = M / BMv;
        const int nbh = 1024 / BMv;   // m-tiles for the 1024-row GEMMs

        // D1: lin_d(first) || GhA || lin_c  (independent; one dispatch)
        {
            GMulti g1;
            g1.d[0] = { cur2, wd2, w_d_b, nullptr, 0, nxt2, 2, 0, nbm };
            g1.d[1] = { hf2, gaW2, ga_bh, GhA, 768, nullptr, 1, 0, nbh };
            g1.d[2] = { hf2, wc2, w_c_b, hn, 256, hn2, 1, 0, nbh };
            const int nb0 = nbm * 2, nb1 = nbh * 6;
            const int nb2 = (l < DEPTHC - 2) ? nbh * 2 : 0;
            g1.n0 = nb0; g1.n01 = nb0 + nb1;
            const int ntot = nb0 + nb1 + nb2;
            if (small) mfma_gemm_multi<64><<<dim3(ntot), blk, 0, stream>>>(g1);
            else       mfma_gemm_multi<128><<<dim3(ntot), blk, 0, stream>>>(g1);
        }
        // D2: pred(first children) || gru_a
        pred_mfma_grua<<<dim3(M / 128 + M / 16), blk, 0, stream>>>(
            nxt2, h2o2, h2o_b, out, spn, l + 1, 2, 0, M / 128,
            spc, GhA, gaT, ga_bx, hf, ApfP);
        // D3: fraternal GRU + combine -> hidden2 (fp16) in Ap2
        if (small) gru_s_fused<64><<<dim3(M / 64, 4), blk, 0, stream>>>(nxt2, spn, gsW2, gsX2, gs_bx, gs_bh, ApfP, Ap2);
        else       gru_s_fused<128><<<dim3(M / 128, 4), blk, 0, stream>>>(nxt2, spn, gsW2, gsX2, gs_bx, gs_bh, ApfP, Ap2);
        // D4: lin_d(second children)
        if (small) mfma_gemm<64><<<dim3(M / 64, 2), blk, 0, stream>>>(Ap2, wd2, w_d_b, nullptr, 0, nxt2, 2, 1);
        else       mfma_gemm<128><<<dim3(M / 128, 2), blk, 0, stream>>>(Ap2, wd2, w_d_b, nullptr, 0, nxt2, 2, 1);
        // D5: pred(second children)
        pred_mfma_grua<<<dim3(M / 128), blk, 0, stream>>>(
            nxt2, h2o2, h2o_b, out, spn, l + 1, 2, 1, M / 128,
            nullptr, nullptr, nullptr, nullptr, nullptr, nullptr);

        // swap ping-pong buffers
        unsigned short* t2;
        t2 = cur2; cur2 = nxt2; nxt2 = t2;
        t2 = spc;  spc  = spn;  spn  = t2;
        float* tf = hf; hf = hn; hn = tf;
        t2 = hf2; hf2 = hn2; hn2 = t2;
    }
}